// Round 9
// baseline (581.966 us; speedup 1.0000x reference)
//
#include <hip/hip_runtime.h>

// HierarchicalRNN T=32,B=16,I=128,H=384,O=32.
// Persistent-register plastic weights; fence-free dataflow sync via
// agent-scope relaxed atomics. Round-9: dedicated pollers WITHOUT spills.
//   block = 640 threads (10 waves):
//     waves 0-7: compute, 3 rows each (round-6-proven 116-VGPR layout)
//     wave 8:    polls noc[t] concurrently with phase A
//     wave 9:    polls noh[t] concurrently with phase B
// Comm words self-flagging (v+2.0, sentinel 0), t-indexed buffers.

#define NT 32
#define NBATCH 16
#define DI 128
#define DH 384
#define DOUT 32
#define CSZ (NT * NBATCH * DH)

__device__ __forceinline__ float retanh_f(float z) {
  z = fmaxf(z, 0.0f);
  float e = __expf(-2.0f * z);
  return (1.0f - e) / (1.0f + e);
}

__device__ __forceinline__ float aldf(const float* p) {
  return __hip_atomic_load(p, __ATOMIC_RELAXED, __HIP_MEMORY_SCOPE_AGENT);
}
__device__ __forceinline__ void pubG(float* p, float v) {
  __hip_atomic_store(p, v, __ATOMIC_RELAXED, __HIP_MEMORY_SCOPE_AGENT);
}

// Poll 6 lane-owned words; all 6 loads in flight per round, one combined check.
__device__ __forceinline__ void gather6G(const float* src, int lane, float arr[6]) {
  const float* p = src + lane;
  float v0, v1, v2, v3, v4, v5;
  for (;;) {
    v0 = aldf(p + 0 * 64);
    v1 = aldf(p + 1 * 64);
    v2 = aldf(p + 2 * 64);
    v3 = aldf(p + 3 * 64);
    v4 = aldf(p + 4 * 64);
    v5 = aldf(p + 5 * 64);
    const bool ok = (v0 != 0.f) & (v1 != 0.f) & (v2 != 0.f) &
                    (v3 != 0.f) & (v4 != 0.f) & (v5 != 0.f);
    if (ok) break;
  }
  arr[0] = v0 - 2.f; arr[1] = v1 - 2.f; arr[2] = v2 - 2.f;
  arr[3] = v3 - 2.f; arr[4] = v4 - 2.f; arr[5] = v5 - 2.f;
}

__global__ __launch_bounds__(640, 3) void hrnn(
    const float* __restrict__ x, const float* __restrict__ Rs,
    const float* __restrict__ Wx, const float* __restrict__ Wc, const float* __restrict__ bc,
    const float* __restrict__ Wch, const float* __restrict__ Whh, const float* __restrict__ bh,
    const float* __restrict__ Wo, const float* __restrict__ Wa, const float* __restrict__ ba,
    const float* __restrict__ kap, float* __restrict__ out, float* __restrict__ comm) {
  const int tid  = threadIdx.x;
  const int lane = tid & 63;
  const int wv   = tid >> 6;
  const int bid  = blockIdx.x;
  const int b = ((bid & 7) << 1) | ((bid >> 3) & 1);
  const int k = bid >> 4;

  float* noc_buf = comm;         // [NT][NBATCH][DH]
  float* noh_buf = comm + CSZ;   // [NT][NBATCH][DH]

  __shared__ float sh_noh[DH];
  __shared__ float sh_noc[DH];

  const bool is_cw    = (wv < 8);
  const bool is_pollC = (wv == 8);
  const bool is_pollH = (wv == 9);
  const int  og0 = k * 24 + wv * 3;          // compute waves: 3 rows
  const bool do_out = (k == 15) && is_cw;

  // compute-wave persistent state (3 rows — round-6 proven register fit)
  float wxc[3][2], wcc[3][6], wchv[3][5], whh[3][6];
  float rWx[3][2], rWc[3][6], rWch[3][5], rWhh[3][6], rWa[3][5];
  float sc[3], shs[3], bcr[3], bar3[3], bhr[3];
  float ohr[6], ocr[6];
  float rWo[4][5];
  float kp[12];
  float xp0 = 0.f, xp1 = 0.f, dtRp = 0.f;

  if (is_cw) {
#pragma unroll
    for (int r = 0; r < 3; ++r) {
      const int og = og0 + r;
#pragma unroll
      for (int j = 0; j < 2; ++j) { rWx[r][j] = fmaxf(Wx[og*DI + j*64 + lane], 0.f); wxc[r][j] = 0.f; }
#pragma unroll
      for (int j = 0; j < 6; ++j) { rWc[r][j] = fmaxf(Wc[og*DH + j*64 + lane], 0.f); wcc[r][j] = 0.f; }
#pragma unroll
      for (int j = 0; j < 5; ++j) { rWch[r][j] = fmaxf(Wch[og*DH + j*64 + lane], 0.f); wchv[r][j] = 0.f; }
#pragma unroll
      for (int j = 0; j < 6; ++j) { rWhh[r][j] = fmaxf(Whh[og*DH + j*64 + lane], 0.f); whh[r][j] = 0.f; }
#pragma unroll
      for (int j = 0; j < 5; ++j) {
        float w = fmaxf(Wa[og*DH + j*64 + lane], 0.f);
        rWa[r][j] = (j == 4 && lane >= 51) ? 0.f : w;   // attn mask: cols>=307 zero
      }
      sc[r] = 0.f; shs[r] = 0.f;
      bcr[r] = bc[og]; bar3[r] = ba[og]; bhr[r] = bh[og];
    }
#pragma unroll
    for (int j = 0; j < 12; ++j) kp[j] = kap[j];
    xp0 = x[b*DI + lane];
    xp1 = x[b*DI + 64 + lane];
    dtRp = 0.02f * Rs[b];
  }
  if (do_out) {
#pragma unroll
    for (int m = 0; m < 4; ++m) {
      const int o = wv * 4 + m;
#pragma unroll
      for (int j = 0; j < 5; ++j) {
        float w = fmaxf(Wo[o*DH + j*64 + lane], 0.f);
        rWo[m][j] = (j == 4 && lane >= 51) ? 0.f : w;  // h2o mask: cols>=307 zero
      }
    }
  }
#pragma unroll
  for (int j = 0; j < 6; ++j) { ohr[j] = 0.f; ocr[j] = 0.f; }

  for (int t = 0; t < NT; ++t) {
    const int toff = t * NBATCH * DH + b * DH;

    __syncthreads();   // B1: sh_noh (= noh[t-1]) ready
    // ---------------- phase A zone (waves 0-7) | wave 8 polls noc[t] ----------------
    if (is_cw) {
      if (t > 0) {
#pragma unroll
        for (int j = 0; j < 6; ++j) ohr[j] = sh_noh[j * 64 + lane];
      }
      const float dtR = dtRp;
      const float x0 = xp0;
      const float x1 = xp1;
      const float oc4s = (lane < 51) ? ocr[4] : -ocr[4];
      const float inC[6] = { ocr[0], ocr[1], ocr[2], ocr[3], oc4s, -ocr[5] };
      float nocr[3];
#pragma unroll
      for (int r = 0; r < 3; ++r) {
        const int og = og0 + r;
        const int dj = og >> 6, dl = og & 63;
        float accA = 0.f, accT = 0.f;
#pragma unroll
        for (int j = 0; j < 5; ++j) accA += rWa[r][j] * ohr[j];
        accT += (rWx[r][0] + wxc[r][0]) * x0;
        accT += (rWx[r][1] + wxc[r][1]) * x1;
#pragma unroll
        for (int j = 0; j < 6; ++j) {
          float term = (rWc[r][j] + wcc[r][j]) * inC[j];
          if (j == dj) term = (lane == dl) ? 0.f : term;  // remove_diag
          accT += term;
        }
#pragma unroll
        for (int mm = 1; mm <= 32; mm <<= 1) {
          accA += __shfl_xor(accA, mm, 64);
          accT += __shfl_xor(accT, mm, 64);
        }
        const float attn = retanh_f(accA + bar3[r]);
        const float tic = accT + bcr[r] + attn;
        sc[r] = 0.8f*sc[r] + 0.2f*tic;
        nocr[r] = retanh_f(sc[r]);
      }
      {  // coalesced publish: lanes 0..2, 12B per wave, ASAP
        float mine = (lane == 0) ? nocr[0] : (lane == 1) ? nocr[1] : nocr[2];
        if (lane < 3) pubG(noc_buf + toff + og0 + lane, mine + 2.0f);
      }
      // overlapped with wave8's poll: plast wxc/wcc (uses OLD oc)
      if (t < NT-1) {
        float axc[2], bxc[2];
#pragma unroll
        for (int j = 0; j < 2; ++j) {
          const float pre = (j == 0) ? x0 : x1;
          axc[j] = dtR*kp[0]*pre; bxc[j] = dtR*(kp[1] + kp[2]*pre);
        }
        float acc_[6], bcc_[6];
#pragma unroll
        for (int j = 0; j < 6; ++j) { acc_[j] = dtR*kp[3]*ocr[j]; bcc_[j] = dtR*(kp[4] + kp[5]*ocr[j]); }
#pragma unroll
        for (int r = 0; r < 3; ++r) {
          const float post = nocr[r];
#pragma unroll
          for (int j = 0; j < 2; ++j)
            wxc[r][j] = fmaxf(fmaf(wxc[r][j], 0.98f, fmaf(bxc[j], post, axc[j])), -rWx[r][j]);
#pragma unroll
          for (int j = 0; j < 6; ++j)
            wcc[r][j] = fmaxf(fmaf(wcc[r][j], 0.98f, fmaf(bcc_[j], post, acc_[j])), -rWc[r][j]);
        }
      }
      // out[t-1] (k==15; overlapped)
      if (do_out && t > 0) {
#pragma unroll
        for (int m = 0; m < 4; ++m) {
          float a = 0.f;
#pragma unroll
          for (int j = 0; j < 5; ++j) a += rWo[m][j] * ohr[j];
#pragma unroll
          for (int mm = 1; mm <= 32; mm <<= 1) a += __shfl_xor(a, mm, 64);
          if (lane == 0) out[(t-1)*NBATCH*DOUT + b*DOUT + wv*4 + m] = a;
        }
      }
    } else if (is_pollC) {
      float tmp[6];
      gather6G(noc_buf + toff, lane, tmp);   // started at B1: overlaps phase A
#pragma unroll
      for (int j = 0; j < 6; ++j) sh_noc[j * 64 + lane] = tmp[j];
    }

    __syncthreads();   // B2: sh_noc (= noc[t]) ready
    // ---------------- phase B zone (waves 0-7) | wave 9 polls noh[t] ----------------
    if (is_cw) {
      float ncr[6];
#pragma unroll
      for (int j = 0; j < 6; ++j) ncr[j] = sh_noc[j * 64 + lane];
      const float dtR = dtRp;
      const float nc4z = (lane < 51) ? ncr[4] : 0.f;
      const float oh4s = (lane < 51) ? ohr[4] : -ohr[4];
      const float inH[6] = { ohr[0], ohr[1], ohr[2], ohr[3], oh4s, -ohr[5] };
      const float inN[5] = { ncr[0], ncr[1], ncr[2], ncr[3], nc4z };
      float nohr[3];
#pragma unroll
      for (int r = 0; r < 3; ++r) {
        const int og = og0 + r;
        const int dj = og >> 6, dl = og & 63;
        float acc = 0.f;
#pragma unroll
        for (int j = 0; j < 5; ++j) acc += (rWch[r][j] + wchv[r][j]) * inN[j];
#pragma unroll
        for (int j = 0; j < 6; ++j) {
          float term = (rWhh[r][j] + whh[r][j]) * inH[j];
          if (j == dj) term = (lane == dl) ? 0.f : term;
          acc += term;
        }
#pragma unroll
        for (int mm = 1; mm <= 32; mm <<= 1) acc += __shfl_xor(acc, mm, 64);
        const float tih = acc + bhr[r];
        shs[r] = 0.8f*shs[r] + 0.2f*tih;
        nohr[r] = retanh_f(shs[r]);
      }
      {  // coalesced publish ASAP
        float mine = (lane == 0) ? nohr[0] : (lane == 1) ? nohr[1] : nohr[2];
        if (lane < 3) pubG(noh_buf + toff + og0 + lane, mine + 2.0f);
      }
      // overlapped with wave9's poll: plast wch/whh + next-step prefetch
      if (t < NT-1) {
        float an_[5], bn_[5];
#pragma unroll
        for (int j = 0; j < 5; ++j) { an_[j] = dtR*kp[6]*ncr[j]; bn_[j] = dtR*(kp[7] + kp[8]*ncr[j]); }
        float ah_[6], bh_[6];
#pragma unroll
        for (int j = 0; j < 6; ++j) { ah_[j] = dtR*kp[9]*ohr[j]; bh_[j] = dtR*(kp[10] + kp[11]*ohr[j]); }
#pragma unroll
        for (int r = 0; r < 3; ++r) {
          const float post = nohr[r];
#pragma unroll
          for (int j = 0; j < 5; ++j)
            wchv[r][j] = fmaxf(fmaf(wchv[r][j], 0.98f, fmaf(bn_[j], post, an_[j])), -rWch[r][j]);
#pragma unroll
          for (int j = 0; j < 6; ++j)
            whh[r][j] = fmaxf(fmaf(whh[r][j], 0.98f, fmaf(bh_[j], post, ah_[j])), -rWhh[r][j]);
        }
        xp0 = x[((t+1)*NBATCH + b)*DI + lane];
        xp1 = x[((t+1)*NBATCH + b)*DI + 64 + lane];
        dtRp = 0.02f * Rs[(t+1)*NBATCH + b];
      }
#pragma unroll
      for (int j = 0; j < 6; ++j) ocr[j] = ncr[j];  // oc <- noc
    } else if (is_pollH) {
      float tmp[6];
      gather6G(noh_buf + toff, lane, tmp);   // overlaps phase B grid-wide
#pragma unroll
      for (int j = 0; j < 6; ++j) sh_noh[j * 64 + lane] = tmp[j];
    }
  }

  // final output row t = NT-1 (sh_noh holds noh[31] from wave 9)
  __syncthreads();
  if (do_out) {
    float oh2[6];
#pragma unroll
    for (int j = 0; j < 6; ++j) oh2[j] = sh_noh[j * 64 + lane];
#pragma unroll
    for (int m = 0; m < 4; ++m) {
      float a = 0.f;
#pragma unroll
      for (int j = 0; j < 5; ++j) a += rWo[m][j] * oh2[j];
#pragma unroll
      for (int mm = 1; mm <= 32; mm <<= 1) a += __shfl_xor(a, mm, 64);
      if (lane == 0) out[(NT-1)*NBATCH*DOUT + b*DOUT + wv*4 + m] = a;
    }
  }
}

extern "C" void kernel_launch(void* const* d_in, const int* in_sizes, int n_in,
                              void* d_out, int out_size, void* d_ws, size_t ws_size,
                              hipStream_t stream) {
  const float* x   = (const float*)d_in[0];
  const float* Rs  = (const float*)d_in[1];
  const float* Wx  = (const float*)d_in[2];
  const float* Wc  = (const float*)d_in[3];
  const float* bc  = (const float*)d_in[4];
  const float* Wch = (const float*)d_in[5];
  const float* Whh = (const float*)d_in[6];
  const float* bh  = (const float*)d_in[7];
  const float* Wo  = (const float*)d_in[8];
  const float* Wa  = (const float*)d_in[9];
  const float* ba  = (const float*)d_in[10];
  const float* kap = (const float*)d_in[11];
  float* out = (float*)d_out;

  float* comm = (float*)d_ws;  // 2*CSZ floats = 1.5 MiB
  hipMemsetAsync(comm, 0, (size_t)2 * CSZ * sizeof(float), stream);

  hipLaunchKernelGGL(hrnn, dim3(256), dim3(640), 0, stream,
                     x, Rs, Wx, Wc, bc, Wch, Whh, bh, Wo, Wa, ba, kap,
                     out, comm);
}

// Round 10
// 265.580 us; speedup vs baseline: 2.1913x; 2.1913x over previous
//
#include <hip/hip_runtime.h>

// HierarchicalRNN T=32,B=16,I=128,H=384,O=32.
// Round-10: PHASE-SPECIALIZED BLOCKS (A/B pipeline).
//   512 blocks x 512 threads (2 blocks/CU, capacity-guaranteed co-resident):
//   A-block(b,k): phase A (attn + tic + sc), owns wxc/wcc, publishes noc[t].
//   B-block(b,k): phase B (tih + sh),        owns wch/whh, publishes noh[t].
// Each block: wave 0 polls the needed vectors (agent-scope, self-flagging
// v+2.0 / sentinel 0, t-indexed buffers), LDS-broadcasts; polls overlap the
// OTHER phase's compute, so detection ~1 round after last publish. Plast /
// out / prefetch run after publish, hidden behind the opposite phase.
// Register pressure per role <= round-6's proven 116 VGPR (half the state).

#define NT 32
#define NBATCH 16
#define DI 128
#define DH 384
#define DOUT 32
#define CSZ (NT * NBATCH * DH)

__device__ __forceinline__ float retanh_f(float z) {
  z = fmaxf(z, 0.0f);
  float e = __expf(-2.0f * z);
  return (1.0f - e) / (1.0f + e);
}

__device__ __forceinline__ float aldf(const float* p) {
  return __hip_atomic_load(p, __ATOMIC_RELAXED, __HIP_MEMORY_SCOPE_AGENT);
}
__device__ __forceinline__ void pubG(float* p, float v) {
  __hip_atomic_store(p, v, __ATOMIC_RELAXED, __HIP_MEMORY_SCOPE_AGENT);
}

// Poll 6 lane-owned words; all loads in flight per round, one combined check.
__device__ __forceinline__ void gather6G(const float* src, int lane, float arr[6]) {
  const float* p = src + lane;
  float v0, v1, v2, v3, v4, v5;
  for (;;) {
    v0 = aldf(p + 0 * 64); v1 = aldf(p + 1 * 64); v2 = aldf(p + 2 * 64);
    v3 = aldf(p + 3 * 64); v4 = aldf(p + 4 * 64); v5 = aldf(p + 5 * 64);
    const bool ok = (v0 != 0.f) & (v1 != 0.f) & (v2 != 0.f) &
                    (v3 != 0.f) & (v4 != 0.f) & (v5 != 0.f);
    if (ok) break;
  }
  arr[0] = v0 - 2.f; arr[1] = v1 - 2.f; arr[2] = v2 - 2.f;
  arr[3] = v3 - 2.f; arr[4] = v4 - 2.f; arr[5] = v5 - 2.f;
}

// Poll 12 words across two buffers (both in flight each round).
__device__ __forceinline__ void gather12G(const float* srcA, const float* srcB,
                                          int lane, float arrA[6], float arrB[6]) {
  const float* pa = srcA + lane;
  const float* pb = srcB + lane;
  float a0,a1,a2,a3,a4,a5,b0,b1,b2,b3,b4,b5;
  for (;;) {
    a0 = aldf(pa + 0*64); a1 = aldf(pa + 1*64); a2 = aldf(pa + 2*64);
    a3 = aldf(pa + 3*64); a4 = aldf(pa + 4*64); a5 = aldf(pa + 5*64);
    b0 = aldf(pb + 0*64); b1 = aldf(pb + 1*64); b2 = aldf(pb + 2*64);
    b3 = aldf(pb + 3*64); b4 = aldf(pb + 4*64); b5 = aldf(pb + 5*64);
    const bool ok = (a0 != 0.f) & (a1 != 0.f) & (a2 != 0.f) &
                    (a3 != 0.f) & (a4 != 0.f) & (a5 != 0.f) &
                    (b0 != 0.f) & (b1 != 0.f) & (b2 != 0.f) &
                    (b3 != 0.f) & (b4 != 0.f) & (b5 != 0.f);
    if (ok) break;
  }
  arrA[0] = a0 - 2.f; arrA[1] = a1 - 2.f; arrA[2] = a2 - 2.f;
  arrA[3] = a3 - 2.f; arrA[4] = a4 - 2.f; arrA[5] = a5 - 2.f;
  arrB[0] = b0 - 2.f; arrB[1] = b1 - 2.f; arrB[2] = b2 - 2.f;
  arrB[3] = b3 - 2.f; arrB[4] = b4 - 2.f; arrB[5] = b5 - 2.f;
}

__global__ __launch_bounds__(512, 4) void hrnn(
    const float* __restrict__ x, const float* __restrict__ Rs,
    const float* __restrict__ Wx, const float* __restrict__ Wc, const float* __restrict__ bc,
    const float* __restrict__ Wch, const float* __restrict__ Whh, const float* __restrict__ bh,
    const float* __restrict__ Wo, const float* __restrict__ Wa, const float* __restrict__ ba,
    const float* __restrict__ kap, float* __restrict__ out, float* __restrict__ comm) {
  const int tid  = threadIdx.x;
  const int lane = tid & 63;
  const int wv   = tid >> 6;
  const int bid  = blockIdx.x;
  const bool roleA = (bid < 256);
  const int sub = bid & 255;
  const int b = ((sub & 7) << 1) | ((sub >> 3) & 1);
  const int k = sub >> 4;
  const int og0 = k * 24 + wv * 3;

  float* noc_buf = comm;         // [NT][NBATCH][DH]
  float* noh_buf = comm + CSZ;   // [NT][NBATCH][DH]

  __shared__ float sh_noc[DH];
  __shared__ float sh_noh[DH];

  if (roleA) {
    // ================= A-block: phase A (cell layer) =================
    float wxc[3][2], wcc[3][6], rWx[3][2], rWc[3][6], rWa[3][5];
    float sc[3], bcr[3], bar3[3], kpA[6];
    float rWo[4][5];
    const bool do_out = (k == 15);
    float ohr[6], ocr[6];

#pragma unroll
    for (int r = 0; r < 3; ++r) {
      const int og = og0 + r;
#pragma unroll
      for (int j = 0; j < 2; ++j) { rWx[r][j] = fmaxf(Wx[og*DI + j*64 + lane], 0.f); wxc[r][j] = 0.f; }
#pragma unroll
      for (int j = 0; j < 6; ++j) { rWc[r][j] = fmaxf(Wc[og*DH + j*64 + lane], 0.f); wcc[r][j] = 0.f; }
#pragma unroll
      for (int j = 0; j < 5; ++j) {
        float w = fmaxf(Wa[og*DH + j*64 + lane], 0.f);
        rWa[r][j] = (j == 4 && lane >= 51) ? 0.f : w;   // attn mask: cols>=307 zero
      }
      sc[r] = 0.f; bcr[r] = bc[og]; bar3[r] = ba[og];
    }
#pragma unroll
    for (int j = 0; j < 6; ++j) kpA[j] = kap[j];
    if (do_out) {
#pragma unroll
      for (int m = 0; m < 4; ++m) {
        const int o = wv * 4 + m;
#pragma unroll
        for (int j = 0; j < 5; ++j) {
          float w = fmaxf(Wo[o*DH + j*64 + lane], 0.f);
          rWo[m][j] = (j == 4 && lane >= 51) ? 0.f : w;  // h2o mask
        }
      }
    }
#pragma unroll
    for (int j = 0; j < 6; ++j) { ohr[j] = 0.f; ocr[j] = 0.f; }
    float xp0 = x[b*DI + lane];
    float xp1 = x[b*DI + 64 + lane];
    float dtRp = 0.02f * Rs[b];

    for (int t = 0; t < NT; ++t) {
      const int toff = t * NBATCH * DH + b * DH;
      if (t > 0) {
        const int poff = toff - NBATCH * DH;
        if (wv == 0) {   // poll noc[t-1] (siblings, ~ready) + noh[t-1] (gates)
          float ta[6], tb[6];
          gather12G(noc_buf + poff, noh_buf + poff, lane, ta, tb);
#pragma unroll
          for (int j = 0; j < 6; ++j) { sh_noc[j*64 + lane] = ta[j]; sh_noh[j*64 + lane] = tb[j]; }
        }
        __syncthreads();
#pragma unroll
        for (int j = 0; j < 6; ++j) { ocr[j] = sh_noc[j*64 + lane]; ohr[j] = sh_noh[j*64 + lane]; }
      }
      const float x0 = xp0, x1 = xp1, dtR = dtRp;
      const float oc4s = (lane < 51) ? ocr[4] : -ocr[4];
      const float inC[6] = { ocr[0], ocr[1], ocr[2], ocr[3], oc4s, -ocr[5] };
      float nocr[3];
#pragma unroll
      for (int r = 0; r < 3; ++r) {
        const int og = og0 + r;
        const int dj = og >> 6, dl = og & 63;
        float accA = 0.f, accT = 0.f;
#pragma unroll
        for (int j = 0; j < 5; ++j) accA += rWa[r][j] * ohr[j];
        accT += (rWx[r][0] + wxc[r][0]) * x0;
        accT += (rWx[r][1] + wxc[r][1]) * x1;
#pragma unroll
        for (int j = 0; j < 6; ++j) {
          float term = (rWc[r][j] + wcc[r][j]) * inC[j];
          if (j == dj) term = (lane == dl) ? 0.f : term;  // remove_diag
          accT += term;
        }
#pragma unroll
        for (int mm = 1; mm <= 32; mm <<= 1) {
          accA += __shfl_xor(accA, mm, 64);
          accT += __shfl_xor(accT, mm, 64);
        }
        const float attn = retanh_f(accA + bar3[r]);
        const float tic = accT + bcr[r] + attn;
        sc[r] = 0.8f*sc[r] + 0.2f*tic;
        nocr[r] = retanh_f(sc[r]);
      }
      {  // publish ASAP: lanes 0..2, 12B/wave
        float mine = (lane == 0) ? nocr[0] : (lane == 1) ? nocr[1] : nocr[2];
        if (lane < 3) pubG(noc_buf + toff + og0 + lane, mine + 2.0f);
      }
      // --- hidden behind B's phase: out, plast, prefetch ---
      if (do_out && t > 0) {
#pragma unroll
        for (int m = 0; m < 4; ++m) {
          float a = 0.f;
#pragma unroll
          for (int j = 0; j < 5; ++j) a += rWo[m][j] * ohr[j];
#pragma unroll
          for (int mm = 1; mm <= 32; mm <<= 1) a += __shfl_xor(a, mm, 64);
          if (lane == 0) out[(t-1)*NBATCH*DOUT + b*DOUT + wv*4 + m] = a;
        }
      }
      if (t < NT-1) {
        float axc[2], bxc[2];
#pragma unroll
        for (int j = 0; j < 2; ++j) {
          const float pre = (j == 0) ? x0 : x1;
          axc[j] = dtR*kpA[0]*pre; bxc[j] = dtR*(kpA[1] + kpA[2]*pre);
        }
        float acc_[6], bcc_[6];
#pragma unroll
        for (int j = 0; j < 6; ++j) { acc_[j] = dtR*kpA[3]*ocr[j]; bcc_[j] = dtR*(kpA[4] + kpA[5]*ocr[j]); }
#pragma unroll
        for (int r = 0; r < 3; ++r) {
          const float post = nocr[r];
#pragma unroll
          for (int j = 0; j < 2; ++j)
            wxc[r][j] = fmaxf(fmaf(wxc[r][j], 0.98f, fmaf(bxc[j], post, axc[j])), -rWx[r][j]);
#pragma unroll
          for (int j = 0; j < 6; ++j)
            wcc[r][j] = fmaxf(fmaf(wcc[r][j], 0.98f, fmaf(bcc_[j], post, acc_[j])), -rWc[r][j]);
        }
        xp0 = x[((t+1)*NBATCH + b)*DI + lane];
        xp1 = x[((t+1)*NBATCH + b)*DI + 64 + lane];
        dtRp = 0.02f * Rs[(t+1)*NBATCH + b];
      }
    }
    // final out row (t = NT-1)
    if (do_out) {
      if (wv == 0) {
        float tmp[6];
        gather6G(noh_buf + (NT-1)*NBATCH*DH + b*DH, lane, tmp);
#pragma unroll
        for (int j = 0; j < 6; ++j) sh_noh[j*64 + lane] = tmp[j];
      }
      __syncthreads();
      float oh2[6];
#pragma unroll
      for (int j = 0; j < 6; ++j) oh2[j] = sh_noh[j*64 + lane];
#pragma unroll
      for (int m = 0; m < 4; ++m) {
        float a = 0.f;
#pragma unroll
        for (int j = 0; j < 5; ++j) a += rWo[m][j] * oh2[j];
#pragma unroll
        for (int mm = 1; mm <= 32; mm <<= 1) a += __shfl_xor(a, mm, 64);
        if (lane == 0) out[(NT-1)*NBATCH*DOUT + b*DOUT + wv*4 + m] = a;
      }
    }
  } else {
    // ================= B-block: phase B (hidden layer) =================
    float wchv[3][5], whh[3][6], rWch[3][5], rWhh[3][6];
    float shs[3], bhr[3], kpB[6];
    float ohr[6];

#pragma unroll
    for (int r = 0; r < 3; ++r) {
      const int og = og0 + r;
#pragma unroll
      for (int j = 0; j < 5; ++j) { rWch[r][j] = fmaxf(Wch[og*DH + j*64 + lane], 0.f); wchv[r][j] = 0.f; }
#pragma unroll
      for (int j = 0; j < 6; ++j) { rWhh[r][j] = fmaxf(Whh[og*DH + j*64 + lane], 0.f); whh[r][j] = 0.f; }
      shs[r] = 0.f; bhr[r] = bh[og];
    }
#pragma unroll
    for (int j = 0; j < 6; ++j) kpB[j] = kap[6 + j];
#pragma unroll
    for (int j = 0; j < 6; ++j) ohr[j] = 0.f;
    float dtRp = 0.02f * Rs[b];

    for (int t = 0; t < NT; ++t) {
      const int toff = t * NBATCH * DH + b * DH;
      if (wv == 0) {   // poll noc[t] (gates) + noh[t-1] (siblings, ~ready)
        if (t == 0) {
          float ta[6];
          gather6G(noc_buf + toff, lane, ta);
#pragma unroll
          for (int j = 0; j < 6; ++j) sh_noc[j*64 + lane] = ta[j];
        } else {
          float ta[6], tb[6];
          gather12G(noc_buf + toff, noh_buf + toff - NBATCH*DH, lane, ta, tb);
#pragma unroll
          for (int j = 0; j < 6; ++j) { sh_noc[j*64 + lane] = ta[j]; sh_noh[j*64 + lane] = tb[j]; }
        }
      }
      __syncthreads();
      float ncr[6];
#pragma unroll
      for (int j = 0; j < 6; ++j) ncr[j] = sh_noc[j*64 + lane];
      if (t > 0) {
#pragma unroll
        for (int j = 0; j < 6; ++j) ohr[j] = sh_noh[j*64 + lane];
      }
      const float dtR = dtRp;
      const float nc4z = (lane < 51) ? ncr[4] : 0.f;
      const float oh4s = (lane < 51) ? ohr[4] : -ohr[4];
      const float inH[6] = { ohr[0], ohr[1], ohr[2], ohr[3], oh4s, -ohr[5] };
      const float inN[5] = { ncr[0], ncr[1], ncr[2], ncr[3], nc4z };
      float nohr[3];
#pragma unroll
      for (int r = 0; r < 3; ++r) {
        const int og = og0 + r;
        const int dj = og >> 6, dl = og & 63;
        float acc = 0.f;
#pragma unroll
        for (int j = 0; j < 5; ++j) acc += (rWch[r][j] + wchv[r][j]) * inN[j];
#pragma unroll
        for (int j = 0; j < 6; ++j) {
          float term = (rWhh[r][j] + whh[r][j]) * inH[j];
          if (j == dj) term = (lane == dl) ? 0.f : term;  // remove_diag
          acc += term;
        }
#pragma unroll
        for (int mm = 1; mm <= 32; mm <<= 1) acc += __shfl_xor(acc, mm, 64);
        const float tih = acc + bhr[r];
        shs[r] = 0.8f*shs[r] + 0.2f*tih;
        nohr[r] = retanh_f(shs[r]);
      }
      {  // publish ASAP
        float mine = (lane == 0) ? nohr[0] : (lane == 1) ? nohr[1] : nohr[2];
        if (lane < 3) pubG(noh_buf + toff + og0 + lane, mine + 2.0f);
      }
      // --- hidden behind A's next phase: plast + prefetch ---
      if (t < NT-1) {
        float an_[5], bn_[5];
#pragma unroll
        for (int j = 0; j < 5; ++j) { an_[j] = dtR*kpB[0]*ncr[j]; bn_[j] = dtR*(kpB[1] + kpB[2]*ncr[j]); }
        float ah_[6], bh_[6];
#pragma unroll
        for (int j = 0; j < 6; ++j) { ah_[j] = dtR*kpB[3]*ohr[j]; bh_[j] = dtR*(kpB[4] + kpB[5]*ohr[j]); }
#pragma unroll
        for (int r = 0; r < 3; ++r) {
          const float post = nohr[r];
#pragma unroll
          for (int j = 0; j < 5; ++j)
            wchv[r][j] = fmaxf(fmaf(wchv[r][j], 0.98f, fmaf(bn_[j], post, an_[j])), -rWch[r][j]);
#pragma unroll
          for (int j = 0; j < 6; ++j)
            whh[r][j] = fmaxf(fmaf(whh[r][j], 0.98f, fmaf(bh_[j], post, ah_[j])), -rWhh[r][j]);
        }
        dtRp = 0.02f * Rs[(t+1)*NBATCH + b];
      }
#pragma unroll
      for (int j = 0; j < 6; ++j) ohr[j] = (j < 6) ? ohr[j] : ohr[j];
      // note: next step's ohr comes from the gather (noh[t]) — not carried.
    }
  }
}

extern "C" void kernel_launch(void* const* d_in, const int* in_sizes, int n_in,
                              void* d_out, int out_size, void* d_ws, size_t ws_size,
                              hipStream_t stream) {
  const float* x   = (const float*)d_in[0];
  const float* Rs  = (const float*)d_in[1];
  const float* Wx  = (const float*)d_in[2];
  const float* Wc  = (const float*)d_in[3];
  const float* bc  = (const float*)d_in[4];
  const float* Wch = (const float*)d_in[5];
  const float* Whh = (const float*)d_in[6];
  const float* bh  = (const float*)d_in[7];
  const float* Wo  = (const float*)d_in[8];
  const float* Wa  = (const float*)d_in[9];
  const float* ba  = (const float*)d_in[10];
  const float* kap = (const float*)d_in[11];
  float* out = (float*)d_out;

  float* comm = (float*)d_ws;  // 2*CSZ floats = 1.5 MiB
  hipMemsetAsync(comm, 0, (size_t)2 * CSZ * sizeof(float), stream);

  hipLaunchKernelGGL(hrnn, dim3(512), dim3(512), 0, stream,
                     x, Rs, Wx, Wc, bc, Wch, Whh, bh, Wo, Wa, ba, kap,
                     out, comm);
}